// Round 14
// baseline (13883.244 us; speedup 1.0000x reference)
//
#include <hip/hip_runtime.h>

#define BB 32      // batch
#define TT 2048    // time steps
#define DD 128     // input dim (layer 1)
#define HH 256     // hidden
#define NTH 512    // threads per block (8 waves -> 2 waves/SIMD)
#define NRANK 32   // blocks (ranks) per group
#define NGRP 8     // groups = 2 dirs x 4 batch-quads
#define HASHK 2654435761u

typedef float f32x4 __attribute__((ext_vector_type(4)));
typedef unsigned int u32;
typedef u32 u32x2 __attribute__((ext_vector_type(2)));
typedef u32 u32x4 __attribute__((ext_vector_type(4)));

__device__ __forceinline__ float sigm(float x)  { return 1.0f / (1.0f + __expf(-x)); }
__device__ __forceinline__ float tanh_f(float x){ return 1.0f - 2.0f / (__expf(2.0f * x) + 1.0f); }

// Persistent bidirectional scan; 256 blocks = 8 groups x 32 ranks, 1 block/CU.
// W in REGISTERS (96 VGPR -- r10/r11: nothing more fits). h exchange:
// (h, tag) packets via IC write-through (sc0 sc1), tag = step + h_bits*HASHK
// (torn reads detected; monotonic tags). NTH=512: 2 waves/SIMD (r7 mechanism).
// POLL-TIMING INVARIANTS (r8/r12/r13 lessons -- do not disturb):
//  - spin loads are issued AFTER the x-dot (earlier => IC poll storm);
//  - the spin's s_waitcnt vmcnt(0) also drains the px prefetch issued at P0:
//    that drain is a LOAD-BEARING delay aligning the first tag check with
//    producer-store visibility (counted waits and faster dots both regress);
//  - fp32 dots: the x-dot's duration is part of the rendezvous timing.
// Per-step floor = producer cell chain + IC store->visibility RTT + h-dot/
// reduce/cell serial chain; this structure measures ~2.9us (L2) / ~2.1us (L1).
template<int KIN, int LAYER>
__global__ __launch_bounds__(NTH, 1)
void lstm_scan(const float* __restrict__ in_seq, long sb, long st,
               const float* __restrict__ wih_f, const float* __restrict__ whh_f,
               const float* __restrict__ bih_f, const float* __restrict__ bhh_f,
               const float* __restrict__ wih_r, const float* __restrict__ whh_r,
               const float* __restrict__ bih_r, const float* __restrict__ bhh_r,
               float* __restrict__ hseed,      // [NGRP][8][HH]
               float* __restrict__ cseed,      // [NGRP][8][HH]
               u32* __restrict__ hbt,          // [NGRP][2par][256j][8b][2]
               float* __restrict__ out1,       // [TT][BB][2H]
               float* __restrict__ acc,        // [TT][BB]
               const float* __restrict__ fcw,  // [2H]
               int never)
{
    constexpr int KINP = KIN + 4;   // zx stride: odd # of 16B slots
    constexpr int HHP  = HH + 4;    // zh stride: 65 slots, odd
    constexpr int C4   = KIN / 4;
    constexpr int XC   = KIN / 128;                  // x chunks (1 / 4)
    constexpr int NPXI = (8 * C4 + NTH - 1) / NTH;   // px f32x4/thread (1 / 2)
    constexpr int RSTR = 36;                         // red2 stride (floats)
    constexpr int PADN = (LAYER == 1) ? 8192 : 5120; // LDS > 80KB: 1 blk/CU

    const int blk  = blockIdx.x;
    const int g    = blk & 7;
    const int rank = blk >> 3;
    const int dir  = g & 1;
    const int bq   = g >> 1;
    const int tid  = threadIdx.x;

    __shared__ __align__(16) float zx[8][KINP];
    __shared__ __align__(16) float zh[8][HHP];
    __shared__ __align__(16) float red2[256 * RSTR];
    __shared__ float gates_s[4][8][9];
    __shared__ float bias_s[32];
    __shared__ float padlds[PADN];
    if (never) padlds[never & (PADN - 1)] = 1.0f;

    const float* wih = dir ? wih_r : wih_f;
    const float* whh = dir ? whh_r : whh_f;
    const float* bih = dir ? bih_r : bih_f;
    const float* bhh = dir ? bhh_r : bhh_f;

    // dot roles: thread = (bh, rg, sl): rows rg*4..+3, b = bh*4..+3, k-slice sl
    const int bh = tid >> 8;        // 0/1
    const int rg = (tid >> 5) & 7;  // 0..7
    const int sl = tid & 31;        // 0..31

    // ---- one-time: W slice -> REGISTERS (bh=0/1 hold identical copies) ----
    f32x4 wx[4][XC], wh[4][2];
    #pragma unroll
    for (int rr = 0; rr < 4; ++rr) {
        const int r = rg * 4 + rr;
        const int grow = (r >> 3) * HH + rank * 8 + (r & 7);
        #pragma unroll
        for (int c = 0; c < XC; ++c)
            wx[rr][c] = *(const f32x4*)(wih + (long)grow * KIN + sl * 4 + 128 * c);
        #pragma unroll
        for (int c = 0; c < 2; ++c)
            wh[rr][c] = *(const f32x4*)(whh + (long)grow * HH + sl * 4 + 128 * c);
    }
    if (tid < 32) {
        const int grow = (tid >> 3) * HH + rank * 8 + (tid & 7);
        bias_s[tid] = bih[grow] + bhh[grow];
    }

    u32* hbt_g = hbt + g * (2 * 256 * 8 * 2);
    float* hs_seed = hseed + g * (8 * HH);
    float* cs_seed = cseed + g * (8 * HH);

    // update roles (tid < 64)
    const int jj2   = tid >> 3;
    const int bl2   = tid & 7;
    const int jglob = rank * 8 + jj2;

    float creg = 0.0f, fcv = 0.0f;
    if (tid < 64 && LAYER == 2) {
        creg = cs_seed[bl2 * HH + jglob];
        fcv  = fcw[dir * HH + jglob];
    }

    // ---- prolog: zx for s=0; seed packets (tag 1) ----
    {
        const int t0 = dir ? (TT - 1) : 0;
        const long tb = (long)t0 * st;
        for (int q = tid; q < 8 * C4; q += NTH) {
            const int bl = q / C4;
            const int k4 = q - bl * C4;
            *(f32x4*)&zx[bl][k4 * 4] =
                *(const f32x4*)(in_seq + (long)(bq * 8 + bl) * sb + tb + k4 * 4);
        }
        if (tid < 64) {
            const float h0 = (LAYER == 1) ? 0.0f : hs_seed[bl2 * HH + jglob];
            const u32 hx = __float_as_uint(h0);
            u32x2 pkt; pkt.x = hx; pkt.y = 1u + hx * HASHK;
            u32* pp = hbt_g + ((0 * 256 + jglob) * 8 + bl2) * 2;
            asm volatile("global_store_dwordx2 %0, %1, off sc0 sc1"
                         :: "v"(pp), "v"(pkt) : "memory");
        }
    }
    __syncthreads();

    for (int s = 0; s < TT; ++s) {
        const int t = dir ? (TT - 1 - s) : s;

        // ---- P0: prefetch x slice for step s+1 (regs; staged in P3) ----
        f32x4 px[NPXI];
        if (s + 1 < TT) {
            const long tb = (long)(dir ? (t - 1) : (t + 1)) * st;
            #pragma unroll
            for (int i = 0; i < NPXI; ++i) {
                const int q = tid + i * NTH;
                if (q < 8 * C4) {
                    const int bl = q / C4;
                    const int k4 = q - bl * C4;
                    px[i] = *(const f32x4*)(in_seq + (long)(bq * 8 + bl) * sb + tb + k4 * 4);
                }
            }
        }

        // ---- P1: x-part of dot (W in regs, z from LDS) ----
        float ac[4][4];
        #pragma unroll
        for (int rr = 0; rr < 4; ++rr)
            #pragma unroll
            for (int b = 0; b < 4; ++b) ac[rr][b] = 0.0f;
        #pragma unroll
        for (int c = 0; c < XC; ++c) {
            f32x4 zv[4];
            #pragma unroll
            for (int b = 0; b < 4; ++b)
                zv[b] = *(const f32x4*)&zx[bh * 4 + b][sl * 4 + 128 * c];
            #pragma unroll
            for (int rr = 0; rr < 4; ++rr) {
                const f32x4 w = wx[rr][c];
                #pragma unroll
                for (int b = 0; b < 4; ++b)
                    ac[rr][b] = fmaf(w.x, zv[b].x, fmaf(w.y, zv[b].y,
                                fmaf(w.z, zv[b].z, fmaf(w.w, zv[b].w, ac[rr][b]))));
            }
        }

        // ---- P2: spin-load tagged h packets (tid<256: thread owns j=tid) ----
        if (tid < 256) {
            const u32 tg = (u32)(s + 1);
            const u32* hp = hbt_g + (((s & 1) * 256 + tid) * 8) * 2;
            u32x4 q0, q1, q2, q3;
            while (true) {
                asm volatile(
                    "global_load_dwordx4 %0, %4, off sc0 sc1\n\t"
                    "global_load_dwordx4 %1, %4, off offset:16 sc0 sc1\n\t"
                    "global_load_dwordx4 %2, %4, off offset:32 sc0 sc1\n\t"
                    "global_load_dwordx4 %3, %4, off offset:48 sc0 sc1\n\t"
                    "s_waitcnt vmcnt(0)"
                    : "=&v"(q0), "=&v"(q1), "=&v"(q2), "=&v"(q3)
                    : "v"(hp) : "memory");
                const bool ok =
                    (q0.y - q0.x * HASHK == tg) && (q0.w - q0.z * HASHK == tg) &&
                    (q1.y - q1.x * HASHK == tg) && (q1.w - q1.z * HASHK == tg) &&
                    (q2.y - q2.x * HASHK == tg) && (q2.w - q2.z * HASHK == tg) &&
                    (q3.y - q3.x * HASHK == tg) && (q3.w - q3.z * HASHK == tg);
                if (ok) break;
                __builtin_amdgcn_s_sleep(1);
            }
            zh[0][tid] = __uint_as_float(q0.x);
            zh[1][tid] = __uint_as_float(q0.z);
            zh[2][tid] = __uint_as_float(q1.x);
            zh[3][tid] = __uint_as_float(q1.z);
            zh[4][tid] = __uint_as_float(q2.x);
            zh[5][tid] = __uint_as_float(q2.z);
            zh[6][tid] = __uint_as_float(q3.x);
            zh[7][tid] = __uint_as_float(q3.z);
        }
        __syncthreads();   // B1: zh ready; zx(s) reads complete

        // ---- P3: h-part of dot + red2 partial writes; stage px -> zx ----
        #pragma unroll
        for (int c = 0; c < 2; ++c) {
            f32x4 zv[4];
            #pragma unroll
            for (int b = 0; b < 4; ++b)
                zv[b] = *(const f32x4*)&zh[bh * 4 + b][sl * 4 + 128 * c];
            #pragma unroll
            for (int rr = 0; rr < 4; ++rr) {
                const f32x4 w = wh[rr][c];
                #pragma unroll
                for (int b = 0; b < 4; ++b)
                    ac[rr][b] = fmaf(w.x, zv[b].x, fmaf(w.y, zv[b].y,
                                fmaf(w.z, zv[b].z, fmaf(w.w, zv[b].w, ac[rr][b]))));
            }
        }
        #pragma unroll
        for (int rr = 0; rr < 4; ++rr)
            #pragma unroll
            for (int b = 0; b < 4; ++b)
                red2[((rg * 4 + rr) * 8 + bh * 4 + b) * RSTR + sl] = ac[rr][b];
        if (s + 1 < TT) {
            #pragma unroll
            for (int i = 0; i < NPXI; ++i) {
                const int q = tid + i * NTH;
                if (q < 8 * C4) {
                    const int bl = q / C4;
                    const int k4 = q - bl * C4;
                    *(f32x4*)&zx[bl][k4 * 4] = px[i];
                }
            }
        }
        __syncthreads();   // B2: red2 + new zx ready

        // ---- P4: reduce 32 k-slices -> gate pre-activations (tid<256) ----
        if (tid < 256) {
            float sg = bias_s[tid >> 3];
            const f32x4* rp = (const f32x4*)&red2[tid * RSTR];
            #pragma unroll
            for (int q = 0; q < 8; ++q) {
                const f32x4 v = rp[q];
                sg += v.x + v.y + v.z + v.w;
            }
            gates_s[tid >> 6][(tid >> 3) & 7][tid & 7] = sg;
        }
        __syncthreads();   // B3: gates ready

        // ---- P5: cell update; packet store FIRST, then outputs ----
        // (no trailing barrier: spin(s+1) gates cross-rank by transitivity;
        //  intra-block LDS hazards all covered by B1/B2/B3)
        if (tid < 64) {
            const float gi = gates_s[0][jj2][bl2];
            const float gf = gates_s[1][jj2][bl2];
            const float gg = gates_s[2][jj2][bl2];
            const float go = gates_s[3][jj2][bl2];
            creg = sigm(gf) * creg + sigm(gi) * tanh_f(gg);
            const float hv = sigm(go) * tanh_f(creg);
            if (s + 1 < TT) {
                const u32 hx = __float_as_uint(hv);
                u32x2 pkt; pkt.x = hx; pkt.y = (u32)(s + 2) + hx * HASHK;
                u32* pp = hbt_g + ((((s + 1) & 1) * 256 + jglob) * 8 + bl2) * 2;
                asm volatile("global_store_dwordx2 %0, %1, off sc0 sc1"
                             :: "v"(pp), "v"(pkt) : "memory");
            }
            if (LAYER == 1) {
                out1[(long)t * (BB * 2 * HH) + (bq * 8 + bl2) * (2 * HH) + dir * HH + jglob] = hv;
                if (s == TT - 1) {
                    hs_seed[bl2 * HH + jglob] = hv;
                    cs_seed[bl2 * HH + jglob] = creg;
                }
            } else {
                float val = hv * fcv;
                val += __shfl_down(val, 32, 64);
                val += __shfl_down(val, 16, 64);
                val += __shfl_down(val, 8, 64);
                if (jj2 == 0) atomicAdd(&acc[t * BB + bq * 8 + bl2], val);
            }
        }
    }
}

__global__ void finalize_k(const float* __restrict__ acc, const float* __restrict__ fcb,
                           float* __restrict__ out)
{
    const int i = blockIdx.x * blockDim.x + threadIdx.x;
    if (i < BB * TT) {
        const int b = i >> 11;
        const int t = i & (TT - 1);
        out[i] = tanhf(acc[t * BB + b] + fcb[0]);
    }
}

extern "C" void kernel_launch(void* const* d_in, const int* in_sizes, int n_in,
                              void* d_out, int out_size, void* d_ws, size_t ws_size,
                              hipStream_t stream) {
    const float* x     = (const float*)d_in[0];
    const float* wih1f = (const float*)d_in[1];
    const float* whh1f = (const float*)d_in[2];
    const float* bih1f = (const float*)d_in[3];
    const float* bhh1f = (const float*)d_in[4];
    const float* wih1r = (const float*)d_in[5];
    const float* whh1r = (const float*)d_in[6];
    const float* bih1r = (const float*)d_in[7];
    const float* bhh1r = (const float*)d_in[8];
    const float* wih2f = (const float*)d_in[9];
    const float* whh2f = (const float*)d_in[10];
    const float* bih2f = (const float*)d_in[11];
    const float* bhh2f = (const float*)d_in[12];
    const float* wih2r = (const float*)d_in[13];
    const float* whh2r = (const float*)d_in[14];
    const float* bih2r = (const float*)d_in[15];
    const float* bhh2r = (const float*)d_in[16];
    const float* fcw   = (const float*)d_in[17];
    const float* fcb   = (const float*)d_in[18];

    char* ws = (char*)d_ws;
    size_t off = 0;
    float* acc  = (float*)(ws + off); off += (size_t)TT * BB * 4;                // 256 KB
    u32* hbt1   = (u32*)(ws + off);   off += (size_t)NGRP * 2 * 256 * 8 * 2 * 4; // 256 KB
    u32* hbt2   = (u32*)(ws + off);   off += (size_t)NGRP * 2 * 256 * 8 * 2 * 4; // 256 KB
    float* hseed = (float*)(ws + off); off += (size_t)NGRP * 8 * HH * 4;         // 64 KB
    float* cseed = (float*)(ws + off); off += (size_t)NGRP * 8 * HH * 4;         // 64 KB
    const size_t clear_bytes = off;
    float* out1 = (float*)(ws + off); off += (size_t)TT * BB * 2 * HH * 4;       // 128 MB

    // acc (atomic target), packet buffers (tag space), seeds: zero each launch
    hipMemsetAsync(d_ws, 0, clear_bytes, stream);

    // layer 1: x (B,T,D)
    lstm_scan<DD, 1><<<NGRP * NRANK, NTH, 0, stream>>>(
        x, (long)TT * DD, (long)DD,
        wih1f, whh1f, bih1f, bhh1f, wih1r, whh1r, bih1r, bhh1r,
        hseed, cseed, hbt1, out1, nullptr, nullptr, 0);

    // layer 2: out1 (T,B,2H); seeds = layer-1 finals
    lstm_scan<2 * HH, 2><<<NGRP * NRANK, NTH, 0, stream>>>(
        out1, (long)(2 * HH), (long)(BB * 2 * HH),
        wih2f, whh2f, bih2f, bhh2f, wih2r, whh2r, bih2r, bhh2r,
        hseed, cseed, hbt2, nullptr, acc, fcw, 0);

    finalize_k<<<(BB * TT + 255) / 256, 256, 0, stream>>>(acc, fcb, (float*)d_out);
}

// Round 15
// 10349.330 us; speedup vs baseline: 1.3415x; 1.3415x over previous
//
#include <hip/hip_runtime.h>

#define BB 32      // batch
#define TT 2048    // time steps
#define DD 128     // input dim (layer 1)
#define HH 256     // hidden
#define NTH 512    // threads per block (8 waves -> 2 waves/SIMD)
#define NRANK 32   // blocks (ranks) per group
#define NGRP 8     // groups = 2 dirs x 4 batch-quads
#define HASHK 2654435761u

typedef float f32x4 __attribute__((ext_vector_type(4)));
typedef unsigned int u32;
typedef u32 u32x2 __attribute__((ext_vector_type(2)));
typedef u32 u32x4 __attribute__((ext_vector_type(4)));

__device__ __forceinline__ float sigm(float x)  { return 1.0f / (1.0f + __expf(-x)); }
__device__ __forceinline__ float tanh_f(float x){ return 1.0f - 2.0f / (__expf(2.0f * x) + 1.0f); }

// Persistent bidirectional scan; 256 blocks = 8 groups x 32 ranks, 1 block/CU
// (LDS padded > 80KB). W in REGISTERS. h exchange: (h, tag) packets via IC
// write-through (sc0 sc1), tag = step + h_bits*HASHK (torn reads detected).
// NTH=512: 2 waves/SIMD.
// RENDEZVOUS-TIMING INVARIANTS (r8/r12/r13/r14 lessons -- all load-bearing):
//  1. spin loads issued AFTER the x-dot (earlier => IC poll storm, r8);
//  2. spin's s_waitcnt vmcnt(0) drains the px prefetch from P0 -- that delay
//     aligns the first tag check with producer-store visibility (counted
//     waits r12 and faster f16 dots r13 both regressed by landing early);
//  3. px->zx staging at END of P5 + trailing loop-end barrier: holds threads
//     64-255 back until this block's producers (tid<64) have issued their
//     packet stores -- removing it lets them front-run the next spin (r14).
template<int KIN, int LAYER>
__global__ __launch_bounds__(NTH, 1)
void lstm_scan(const float* __restrict__ in_seq, long sb, long st,
               const float* __restrict__ wih_f, const float* __restrict__ whh_f,
               const float* __restrict__ bih_f, const float* __restrict__ bhh_f,
               const float* __restrict__ wih_r, const float* __restrict__ whh_r,
               const float* __restrict__ bih_r, const float* __restrict__ bhh_r,
               float* __restrict__ hseed,      // [NGRP][8][HH]
               float* __restrict__ cseed,      // [NGRP][8][HH]
               u32* __restrict__ hbt,          // [NGRP][2par][256j][8b][2]
               float* __restrict__ out1,       // [TT][BB][2H]
               float* __restrict__ acc,        // [TT][BB]
               const float* __restrict__ fcw,  // [2H]
               int never)
{
    constexpr int KINP = KIN + 4;   // zx stride: odd # of 16B slots
    constexpr int HHP  = HH + 4;    // zh stride: 65 slots, odd
    constexpr int C4   = KIN / 4;
    constexpr int XC   = KIN / 128;                  // x chunks (1 / 4)
    constexpr int NPXI = (8 * C4 + NTH - 1) / NTH;   // px f32x4/thread (1 / 2)
    constexpr int RSTR = 36;                         // red2 stride (floats)
    constexpr int PADN = (LAYER == 1) ? 8192 : 5120; // LDS > 80KB: 1 blk/CU

    const int blk  = blockIdx.x;
    const int g    = blk & 7;
    const int rank = blk >> 3;
    const int dir  = g & 1;
    const int bq   = g >> 1;
    const int tid  = threadIdx.x;

    __shared__ __align__(16) float zx[8][KINP];
    __shared__ __align__(16) float zh[8][HHP];
    __shared__ __align__(16) float red2[256 * RSTR];
    __shared__ float gates_s[4][8][9];
    __shared__ float bias_s[32];
    __shared__ float padlds[PADN];
    if (never) padlds[never & (PADN - 1)] = 1.0f;

    const float* wih = dir ? wih_r : wih_f;
    const float* whh = dir ? whh_r : whh_f;
    const float* bih = dir ? bih_r : bih_f;
    const float* bhh = dir ? bhh_r : bhh_f;

    // dot roles: thread = (bh, rg, sl): rows rg*4..+3, b = bh*4..+3, k-slice sl
    const int bh = tid >> 8;        // 0/1
    const int rg = (tid >> 5) & 7;  // 0..7
    const int sl = tid & 31;        // 0..31

    // ---- one-time: W slice -> REGISTERS (bh=0/1 hold identical copies) ----
    f32x4 wx[4][XC], wh[4][2];
    #pragma unroll
    for (int rr = 0; rr < 4; ++rr) {
        const int r = rg * 4 + rr;
        const int grow = (r >> 3) * HH + rank * 8 + (r & 7);
        #pragma unroll
        for (int c = 0; c < XC; ++c)
            wx[rr][c] = *(const f32x4*)(wih + (long)grow * KIN + sl * 4 + 128 * c);
        #pragma unroll
        for (int c = 0; c < 2; ++c)
            wh[rr][c] = *(const f32x4*)(whh + (long)grow * HH + sl * 4 + 128 * c);
    }
    if (tid < 32) {
        const int grow = (tid >> 3) * HH + rank * 8 + (tid & 7);
        bias_s[tid] = bih[grow] + bhh[grow];
    }

    u32* hbt_g = hbt + g * (2 * 256 * 8 * 2);
    float* hs_seed = hseed + g * (8 * HH);
    float* cs_seed = cseed + g * (8 * HH);

    // update roles (tid < 64)
    const int jj2   = tid >> 3;
    const int bl2   = tid & 7;
    const int jglob = rank * 8 + jj2;

    float creg = 0.0f, fcv = 0.0f;
    if (tid < 64 && LAYER == 2) {
        creg = cs_seed[bl2 * HH + jglob];
        fcv  = fcw[dir * HH + jglob];
    }

    // ---- prolog: zx for s=0; seed packets (tag 1) ----
    {
        const int t0 = dir ? (TT - 1) : 0;
        const long tb = (long)t0 * st;
        for (int q = tid; q < 8 * C4; q += NTH) {
            const int bl = q / C4;
            const int k4 = q - bl * C4;
            *(f32x4*)&zx[bl][k4 * 4] =
                *(const f32x4*)(in_seq + (long)(bq * 8 + bl) * sb + tb + k4 * 4);
        }
        if (tid < 64) {
            const float h0 = (LAYER == 1) ? 0.0f : hs_seed[bl2 * HH + jglob];
            const u32 hx = __float_as_uint(h0);
            u32x2 pkt; pkt.x = hx; pkt.y = 1u + hx * HASHK;
            u32* pp = hbt_g + ((0 * 256 + jglob) * 8 + bl2) * 2;
            asm volatile("global_store_dwordx2 %0, %1, off sc0 sc1"
                         :: "v"(pp), "v"(pkt) : "memory");
        }
    }
    __syncthreads();

    for (int s = 0; s < TT; ++s) {
        const int t = dir ? (TT - 1 - s) : s;

        // ---- P0: prefetch x slice for step s+1 ----
        f32x4 px[NPXI];
        if (s + 1 < TT) {
            const long tb = (long)(dir ? (t - 1) : (t + 1)) * st;
            #pragma unroll
            for (int i = 0; i < NPXI; ++i) {
                const int q = tid + i * NTH;
                if (q < 8 * C4) {
                    const int bl = q / C4;
                    const int k4 = q - bl * C4;
                    px[i] = *(const f32x4*)(in_seq + (long)(bq * 8 + bl) * sb + tb + k4 * 4);
                }
            }
        }

        // ---- P1: x-part of dot (W in regs, z from LDS) ----
        float ac[4][4];
        #pragma unroll
        for (int rr = 0; rr < 4; ++rr)
            #pragma unroll
            for (int b = 0; b < 4; ++b) ac[rr][b] = 0.0f;
        #pragma unroll
        for (int c = 0; c < XC; ++c) {
            f32x4 zv[4];
            #pragma unroll
            for (int b = 0; b < 4; ++b)
                zv[b] = *(const f32x4*)&zx[bh * 4 + b][sl * 4 + 128 * c];
            #pragma unroll
            for (int rr = 0; rr < 4; ++rr) {
                const f32x4 w = wx[rr][c];
                #pragma unroll
                for (int b = 0; b < 4; ++b)
                    ac[rr][b] = fmaf(w.x, zv[b].x, fmaf(w.y, zv[b].y,
                                fmaf(w.z, zv[b].z, fmaf(w.w, zv[b].w, ac[rr][b]))));
            }
        }

        // ---- P2: spin-load tagged h packets (tid<256: thread owns j=tid) ----
        if (tid < 256) {
            const u32 tg = (u32)(s + 1);
            const u32* hp = hbt_g + (((s & 1) * 256 + tid) * 8) * 2;
            u32x4 q0, q1, q2, q3;
            while (true) {
                asm volatile(
                    "global_load_dwordx4 %0, %4, off sc0 sc1\n\t"
                    "global_load_dwordx4 %1, %4, off offset:16 sc0 sc1\n\t"
                    "global_load_dwordx4 %2, %4, off offset:32 sc0 sc1\n\t"
                    "global_load_dwordx4 %3, %4, off offset:48 sc0 sc1\n\t"
                    "s_waitcnt vmcnt(0)"
                    : "=&v"(q0), "=&v"(q1), "=&v"(q2), "=&v"(q3)
                    : "v"(hp) : "memory");
                const bool ok =
                    (q0.y - q0.x * HASHK == tg) && (q0.w - q0.z * HASHK == tg) &&
                    (q1.y - q1.x * HASHK == tg) && (q1.w - q1.z * HASHK == tg) &&
                    (q2.y - q2.x * HASHK == tg) && (q2.w - q2.z * HASHK == tg) &&
                    (q3.y - q3.x * HASHK == tg) && (q3.w - q3.z * HASHK == tg);
                if (ok) break;
                __builtin_amdgcn_s_sleep(1);
            }
            zh[0][tid] = __uint_as_float(q0.x);
            zh[1][tid] = __uint_as_float(q0.z);
            zh[2][tid] = __uint_as_float(q1.x);
            zh[3][tid] = __uint_as_float(q1.z);
            zh[4][tid] = __uint_as_float(q2.x);
            zh[5][tid] = __uint_as_float(q2.z);
            zh[6][tid] = __uint_as_float(q3.x);
            zh[7][tid] = __uint_as_float(q3.z);
        }
        __syncthreads();   // B1: zh ready; zx(s) reads complete

        // ---- P3: h-part of dot + red2 partial writes ----
        #pragma unroll
        for (int c = 0; c < 2; ++c) {
            f32x4 zv[4];
            #pragma unroll
            for (int b = 0; b < 4; ++b)
                zv[b] = *(const f32x4*)&zh[bh * 4 + b][sl * 4 + 128 * c];
            #pragma unroll
            for (int rr = 0; rr < 4; ++rr) {
                const f32x4 w = wh[rr][c];
                #pragma unroll
                for (int b = 0; b < 4; ++b)
                    ac[rr][b] = fmaf(w.x, zv[b].x, fmaf(w.y, zv[b].y,
                                fmaf(w.z, zv[b].z, fmaf(w.w, zv[b].w, ac[rr][b]))));
            }
        }
        #pragma unroll
        for (int rr = 0; rr < 4; ++rr)
            #pragma unroll
            for (int b = 0; b < 4; ++b)
                red2[((rg * 4 + rr) * 8 + bh * 4 + b) * RSTR + sl] = ac[rr][b];
        __syncthreads();   // B2: red2 ready

        // ---- P4: reduce 32 k-slices -> gate pre-activations (tid<256) ----
        if (tid < 256) {
            float sg = bias_s[tid >> 3];
            const f32x4* rp = (const f32x4*)&red2[tid * RSTR];
            #pragma unroll
            for (int q = 0; q < 8; ++q) {
                const f32x4 v = rp[q];
                sg += v.x + v.y + v.z + v.w;
            }
            gates_s[tid >> 6][(tid >> 3) & 7][tid & 7] = sg;
        }
        __syncthreads();   // B3: gates ready

        // ---- P5: cell update, packet store, outputs; stage px -> zx ----
        if (tid < 64) {
            const float gi = gates_s[0][jj2][bl2];
            const float gf = gates_s[1][jj2][bl2];
            const float gg = gates_s[2][jj2][bl2];
            const float go = gates_s[3][jj2][bl2];
            creg = sigm(gf) * creg + sigm(gi) * tanh_f(gg);
            const float hv = sigm(go) * tanh_f(creg);
            if (s + 1 < TT) {
                const u32 hx = __float_as_uint(hv);
                u32x2 pkt; pkt.x = hx; pkt.y = (u32)(s + 2) + hx * HASHK;
                u32* pp = hbt_g + ((((s + 1) & 1) * 256 + jglob) * 8 + bl2) * 2;
                asm volatile("global_store_dwordx2 %0, %1, off sc0 sc1"
                             :: "v"(pp), "v"(pkt) : "memory");
            }
            if (LAYER == 1) {
                out1[(long)t * (BB * 2 * HH) + (bq * 8 + bl2) * (2 * HH) + dir * HH + jglob] = hv;
                if (s == TT - 1) {
                    hs_seed[bl2 * HH + jglob] = hv;
                    cs_seed[bl2 * HH + jglob] = creg;
                }
            } else {
                float val = hv * fcv;
                val += __shfl_down(val, 32, 64);
                val += __shfl_down(val, 16, 64);
                val += __shfl_down(val, 8, 64);
                if (jj2 == 0) atomicAdd(&acc[t * BB + bq * 8 + bl2], val);
            }
        }
        if (s + 1 < TT) {
            #pragma unroll
            for (int i = 0; i < NPXI; ++i) {
                const int q = tid + i * NTH;
                if (q < 8 * C4) {
                    const int bl = q / C4;
                    const int k4 = q - bl * C4;
                    *(f32x4*)&zx[bl][k4 * 4] = px[i];
                }
            }
        }
        __syncthreads();   // B4: loop-end (new zx ready; holds back front-runners)
    }
}

__global__ void finalize_k(const float* __restrict__ acc, const float* __restrict__ fcb,
                           float* __restrict__ out)
{
    const int i = blockIdx.x * blockDim.x + threadIdx.x;
    if (i < BB * TT) {
        const int b = i >> 11;
        const int t = i & (TT - 1);
        out[i] = tanhf(acc[t * BB + b] + fcb[0]);
    }
}

extern "C" void kernel_launch(void* const* d_in, const int* in_sizes, int n_in,
                              void* d_out, int out_size, void* d_ws, size_t ws_size,
                              hipStream_t stream) {
    const float* x     = (const float*)d_in[0];
    const float* wih1f = (const float*)d_in[1];
    const float* whh1f = (const float*)d_in[2];
    const float* bih1f = (const float*)d_in[3];
    const float* bhh1f = (const float*)d_in[4];
    const float* wih1r = (const float*)d_in[5];
    const float* whh1r = (const float*)d_in[6];
    const float* bih1r = (const float*)d_in[7];
    const float* bhh1r = (const float*)d_in[8];
    const float* wih2f = (const float*)d_in[9];
    const float* whh2f = (const float*)d_in[10];
    const float* bih2f = (const float*)d_in[11];
    const float* bhh2f = (const float*)d_in[12];
    const float* wih2r = (const float*)d_in[13];
    const float* whh2r = (const float*)d_in[14];
    const float* bih2r = (const float*)d_in[15];
    const float* bhh2r = (const float*)d_in[16];
    const float* fcw   = (const float*)d_in[17];
    const float* fcb   = (const float*)d_in[18];

    char* ws = (char*)d_ws;
    size_t off = 0;
    float* acc  = (float*)(ws + off); off += (size_t)TT * BB * 4;                // 256 KB
    u32* hbt1   = (u32*)(ws + off);   off += (size_t)NGRP * 2 * 256 * 8 * 2 * 4; // 256 KB
    u32* hbt2   = (u32*)(ws + off);   off += (size_t)NGRP * 2 * 256 * 8 * 2 * 4; // 256 KB
    float* hseed = (float*)(ws + off); off += (size_t)NGRP * 8 * HH * 4;         // 64 KB
    float* cseed = (float*)(ws + off); off += (size_t)NGRP * 8 * HH * 4;         // 64 KB
    const size_t clear_bytes = off;
    float* out1 = (float*)(ws + off); off += (size_t)TT * BB * 2 * HH * 4;       // 128 MB

    // acc (atomic target), packet buffers (tag space), seeds: zero each launch
    hipMemsetAsync(d_ws, 0, clear_bytes, stream);

    // layer 1: x (B,T,D)
    lstm_scan<DD, 1><<<NGRP * NRANK, NTH, 0, stream>>>(
        x, (long)TT * DD, (long)DD,
        wih1f, whh1f, bih1f, bhh1f, wih1r, whh1r, bih1r, bhh1r,
        hseed, cseed, hbt1, out1, nullptr, nullptr, 0);

    // layer 2: out1 (T,B,2H); seeds = layer-1 finals
    lstm_scan<2 * HH, 2><<<NGRP * NRANK, NTH, 0, stream>>>(
        out1, (long)(2 * HH), (long)(BB * 2 * HH),
        wih2f, whh2f, bih2f, bhh2f, wih2r, whh2r, bih2r, bhh2r,
        hseed, cseed, hbt2, nullptr, acc, fcw, 0);

    finalize_k<<<(BB * TT + 255) / 256, 256, 0, stream>>>(acc, fcb, (float*)d_out);
}